// Round 6
// baseline (835.059 us; speedup 1.0000x reference)
//
#include <hip/hip_runtime.h>
#include <hip/hip_fp16.h>

#define N_NODES 50000
#define N_EDGES 800000
#define IN_DIM 128
#define OUT_DIM 64
#define OUT_DATA 32

#define BUCKET_SHIFT 7
#define BUCKET_SIZE 128                                      // nodes per bucket
#define NBUCK ((N_NODES + BUCKET_SIZE - 1) / BUCKET_SIZE)    // 391
#define NBLK_BIN 128
#define BIN_THREADS 1024
#define EPB ((N_EDGES + NBLK_BIN - 1) / NBLK_BIN)            // 6250

// ---------------- workspace layout (bytes) ----------------
#define OFF_DEG     0u          // int[N]            -> pad 200704
#define OFF_GCNT    200704u     // int[NBUCK]        -> pad 2048
#define OFF_GBASE   202752u     // int[NBUCK+1]      -> pad 2048
#define OFF_PERBLK  204800u     // int[128*391]      -> pad 200704
#define OFF_EREC    405504u     // int[E] packed (local<<16)|src   = 3.2 MB
#define OFF_XW      3605504u    // half[N*64] prescaled by dinv    = 6.4 MB
#define OFF_XW2     10005504u   // half[N*64] prescaled by dinv
#define OFF_WC      16405504u   // float[64*32]
#define OFF_BC      16413696u   // float[32]
// total ~16.4 MB

// Detect whether edge_index is stored as int64 (high dwords all zero) or int32.
__device__ __forceinline__ bool ei_is64(const int* ei) {
    int o = 0;
#pragma unroll
    for (int k = 0; k < 16; ++k) o |= ei[2 * k + 1];
    return o == 0;
}
__device__ __forceinline__ int load_ei(const int* ei, long long flat, bool is64) {
    return is64 ? (int)(((const long long*)ei)[flat]) : ei[flat];
}

// ---------------- zero deg + gcnt (202752 B = 12672 int4) ----------------
__global__ void zero_kernel(int4* __restrict__ p) {
    int i = blockIdx.x * 256 + threadIdx.x;
    if (i < 12672) p[i] = make_int4(0, 0, 0, 0);
}

// ---------------- pass 1: bucket histogram (per-block LDS) + node degrees ----------------
__global__ __launch_bounds__(BIN_THREADS) void hist_kernel(const int* __restrict__ ei,
                                                           int* __restrict__ deg,
                                                           int* __restrict__ gcnt,
                                                           int* __restrict__ perblk) {
    __shared__ int lh[NBUCK];
    int t = threadIdx.x;
    for (int i = t; i < NBUCK; i += BIN_THREADS) lh[i] = 0;
    __syncthreads();
    bool is64 = ei_is64(ei);
    int e0 = blockIdx.x * EPB;
    int e1 = e0 + EPB; if (e1 > N_EDGES) e1 = N_EDGES;
    for (int e = e0 + t; e < e1; e += BIN_THREADS) {
        int d = load_ei(ei, (long long)N_EDGES + e, is64);
        atomicAdd(&lh[d >> BUCKET_SHIFT], 1);
        atomicAdd(&deg[d], 1);               // fire-and-forget
    }
    __syncthreads();
    for (int i = t; i < NBUCK; i += BIN_THREADS)
        perblk[blockIdx.x * NBUCK + i] = atomicAdd(&gcnt[i], lh[i]);
}

// ---------------- prefix over buckets; fused head-weight folding ----------------
__global__ void scanP_kernel(const int* __restrict__ gcnt, int* __restrict__ gbase,
                             const float* __restrict__ Wp1, const float* __restrict__ bp1,
                             const float* __restrict__ Wp2, const float* __restrict__ bp2,
                             float* __restrict__ Wc, float* __restrict__ bc) {
    __shared__ int tmp[512];
    int t = threadIdx.x;
    int v = (t < NBUCK) ? gcnt[t] : 0;
    tmp[t] = v;
    __syncthreads();
    for (int o = 1; o < 512; o <<= 1) {
        int x = tmp[t];
        if (t >= o) x += tmp[t - o];
        __syncthreads();
        tmp[t] = x;
        __syncthreads();
    }
    if (t < NBUCK) gbase[t] = tmp[t] - v;
    if (t == NBUCK - 1) gbase[NBUCK] = tmp[t];
    // head fold: Wc = Wp1@Wp2, bc = bp1@Wp2+bp2
    for (int idx = t; idx < 64 * 32; idx += 512) {
        int r = idx >> 5, j = idx & 31;
        float s = 0.0f;
        for (int k = 0; k < 64; ++k) s += Wp1[r * 64 + k] * Wp2[k * 32 + j];
        Wc[idx] = s;
    }
    if (t < 32) {
        float s = bp2[t];
        for (int k = 0; k < 64; ++k) s += bp1[k] * Wp2[k * 32 + t];
        bc[t] = s;
    }
}

// ---------------- pass 2: scatter packed records grouped by bucket ----------------
__global__ __launch_bounds__(BIN_THREADS) void scat_kernel(const int* __restrict__ ei,
                                                           const int* __restrict__ gbase,
                                                           const int* __restrict__ perblk,
                                                           int* __restrict__ erec) {
    __shared__ int lh[NBUCK];
    int t = threadIdx.x;
    for (int i = t; i < NBUCK; i += BIN_THREADS) lh[i] = 0;
    __syncthreads();
    bool is64 = ei_is64(ei);
    int e0 = blockIdx.x * EPB;
    int e1 = e0 + EPB; if (e1 > N_EDGES) e1 = N_EDGES;
    for (int e = e0 + t; e < e1; e += BIN_THREADS) {
        int s = load_ei(ei, e, is64);
        int d = load_ei(ei, (long long)N_EDGES + e, is64);
        int b = d >> BUCKET_SHIFT;
        int slot = atomicAdd(&lh[b], 1);
        int pos = gbase[b] + perblk[blockIdx.x * NBUCK + b] + slot;
        erec[pos] = s | ((d & (BUCKET_SIZE - 1)) << 16);   // s<65536, local<128
    }
}

// ---------------- dense GEMM: Yh[row] = (X[row]@W) * dinv[row], fp16 ----------------
template <int K>
__global__ __launch_bounds__(256) void gemm64_kernel(const float* __restrict__ X,
                                                     const float* __restrict__ W,
                                                     const int* __restrict__ deg,
                                                     __half* __restrict__ Yh, int N) {
    __shared__ float Wl[K * 64];
    int t = threadIdx.x;
    for (int i = t; i < K * 16; i += 256)
        reinterpret_cast<float4*>(Wl)[i] = reinterpret_cast<const float4*>(W)[i];
    __syncthreads();
    int row = blockIdx.x * 256 + t;
    if (row >= N) return;
    float acc[64];
#pragma unroll
    for (int c = 0; c < 64; ++c) acc[c] = 0.0f;
    const float4* xr = reinterpret_cast<const float4*>(X + (size_t)row * K);
    for (int k4 = 0; k4 < K / 4; ++k4) {
        float4 xv = xr[k4];
#pragma unroll
        for (int kk = 0; kk < 4; ++kk) {
            float xs = (kk == 0) ? xv.x : (kk == 1) ? xv.y : (kk == 2) ? xv.z : xv.w;
            const float4* wr = reinterpret_cast<const float4*>(&Wl[(k4 * 4 + kk) * 64]);
#pragma unroll
            for (int c4 = 0; c4 < 16; ++c4) {
                float4 wv = wr[c4];
                acc[c4 * 4 + 0] += xs * wv.x;
                acc[c4 * 4 + 1] += xs * wv.y;
                acc[c4 * 4 + 2] += xs * wv.z;
                acc[c4 * 4 + 3] += xs * wv.w;
            }
        }
    }
    float di = rsqrtf((float)deg[row] + 1.0f);
    __half2* yr = reinterpret_cast<__half2*>(Yh + (size_t)row * 64);
#pragma unroll
    for (int c2 = 0; c2 < 32; ++c2)
        yr[c2] = __floats2half2_rn(acc[2 * c2] * di, acc[2 * c2 + 1] * di);
}

// ---------------- edge-parallel gather into LDS accumulator tile ----------------
__device__ __forceinline__ void gather_bucket(const __half* __restrict__ xwp,
                                              const int* __restrict__ erec,
                                              float* accS, int ebeg, int eend,
                                              int wv, int lane) {
    int cnt = eend - ebeg;
    int per = (cnt + 15) >> 4;                 // 16 waves
    int b0 = ebeg + wv * per;
    int b1 = b0 + per; if (b1 > eend) b1 = eend;
    int e = b0;
    for (; e + 4 <= b1; e += 4) {
        int r0 = erec[e + 0], r1 = erec[e + 1], r2 = erec[e + 2], r3 = erec[e + 3];
        float v0 = __half2float(xwp[((r0 & 0xFFFF) << 6) + lane]);
        float v1 = __half2float(xwp[((r1 & 0xFFFF) << 6) + lane]);
        float v2 = __half2float(xwp[((r2 & 0xFFFF) << 6) + lane]);
        float v3 = __half2float(xwp[((r3 & 0xFFFF) << 6) + lane]);
        atomicAdd(&accS[((r0 >> 16) << 6) + lane], v0);
        atomicAdd(&accS[((r1 >> 16) << 6) + lane], v1);
        atomicAdd(&accS[((r2 >> 16) << 6) + lane], v2);
        atomicAdd(&accS[((r3 >> 16) << 6) + lane], v3);
    }
    for (; e < b1; ++e) {
        int r = erec[e];
        atomicAdd(&accS[((r >> 16) << 6) + lane],
                  __half2float(xwp[((r & 0xFFFF) << 6) + lane]));
    }
}

// ---------------- layer1: bucket agg + tanh + @W2, writes prescaled fp16 xw2 ----------------
__global__ __launch_bounds__(1024) void aggA_kernel(
    const __half* __restrict__ xwp, const int* __restrict__ erec,
    const int* __restrict__ gbase, const int* __restrict__ deg,
    const float* __restrict__ b1v, const float* __restrict__ W2,
    __half* __restrict__ xw2p) {
    __shared__ float accS[BUCKET_SIZE * 64];   // 32 KB
    __shared__ float W2l[64 * 64];             // 16 KB
    __shared__ float rowS[16][64];             // 4 KB
    int t = threadIdx.x, lane = t & 63, wv = t >> 6;
    reinterpret_cast<float4*>(W2l)[t] = reinterpret_cast<const float4*>(W2)[t];  // 1024 float4 = 4096 f
    for (int i = t; i < BUCKET_SIZE * 64; i += 1024) accS[i] = 0.0f;
    __syncthreads();
    int bucket = blockIdx.x;
    int ebeg = gbase[bucket], eend = gbase[bucket + 1];
    gather_bucket(xwp, erec, accS, ebeg, eend, wv, lane);
    __syncthreads();
    int nodeBase = bucket << BUCKET_SHIFT;
#pragma unroll
    for (int k = 0; k < 8; ++k) {
        int nl = (wv << 3) + k;
        int node = nodeBase + nl;
        if (node >= N_NODES) break;
        float a = accS[(nl << 6) + lane];
        float selfv = __half2float(xwp[(node << 6) + lane]);
        float di = rsqrtf((float)deg[node] + 1.0f);
        float h = tanhf((a + selfv) * di + b1v[lane]);
        rowS[wv][lane] = h;                    // wave-private
        float o = 0.0f;
#pragma unroll
        for (int f4 = 0; f4 < 16; ++f4) {
            float4 rv = reinterpret_cast<const float4*>(&rowS[wv][0])[f4];
            o += rv.x * W2l[(f4 * 4 + 0) * 64 + lane];
            o += rv.y * W2l[(f4 * 4 + 1) * 64 + lane];
            o += rv.z * W2l[(f4 * 4 + 2) * 64 + lane];
            o += rv.w * W2l[(f4 * 4 + 3) * 64 + lane];
        }
        xw2p[(node << 6) + lane] = __float2half_rn(o * di);   // prescale for layer 2
    }
}

// ---------------- layer2: bucket agg + emb + tanh + head + log_softmax ----------------
__global__ __launch_bounds__(1024) void aggB_kernel(
    const __half* __restrict__ xw2p, const int* __restrict__ erec,
    const int* __restrict__ gbase, const int* __restrict__ deg,
    const float* __restrict__ b2v, const float* __restrict__ Wc,
    const float* __restrict__ bc, float* __restrict__ embOut,
    float* __restrict__ logitsOut) {
    __shared__ float accS[BUCKET_SIZE * 64];   // 32 KB
    __shared__ float Wcl[64 * 32];             // 8 KB
    __shared__ float rowS[16][64];             // 4 KB
    __shared__ float bcl[32];
    int t = threadIdx.x, lane = t & 63, wv = t >> 6;
    if (t < 512) reinterpret_cast<float4*>(Wcl)[t] = reinterpret_cast<const float4*>(Wc)[t];
    if (t < 32) bcl[t] = bc[t];
    for (int i = t; i < BUCKET_SIZE * 64; i += 1024) accS[i] = 0.0f;
    __syncthreads();
    int bucket = blockIdx.x;
    int ebeg = gbase[bucket], eend = gbase[bucket + 1];
    gather_bucket(xw2p, erec, accS, ebeg, eend, wv, lane);
    __syncthreads();
    int nodeBase = bucket << BUCKET_SHIFT;
#pragma unroll
    for (int k = 0; k < 8; ++k) {
        int nl = (wv << 3) + k;
        int node = nodeBase + nl;
        if (node >= N_NODES) break;
        float a = accS[(nl << 6) + lane];
        float selfv = __half2float(xw2p[(node << 6) + lane]);
        float di = rsqrtf((float)deg[node] + 1.0f);
        float v = (a + selfv) * di + b2v[lane];
        embOut[(node << 6) + lane] = v;
        rowS[wv][lane] = tanhf(v);             // wave-private
        int j = lane & 31, half = lane >> 5;
        float p = half ? 0.0f : bcl[j];
#pragma unroll
        for (int f4 = 0; f4 < 8; ++f4) {
            float4 rv = reinterpret_cast<const float4*>(&rowS[wv][half * 32])[f4];
            int fb = half * 32 + f4 * 4;
            p += rv.x * Wcl[(fb + 0) * 32 + j];
            p += rv.y * Wcl[(fb + 1) * 32 + j];
            p += rv.z * Wcl[(fb + 2) * 32 + j];
            p += rv.w * Wcl[(fb + 3) * 32 + j];
        }
        p += __shfl_down(p, 32);               // lanes 0..31 hold full logits
        float m = p;
#pragma unroll
        for (int o = 16; o > 0; o >>= 1) m = fmaxf(m, __shfl_xor(m, o, 32));
        float ex = __expf(p - m);
        float s = ex;
#pragma unroll
        for (int o = 16; o > 0; o >>= 1) s += __shfl_xor(s, o, 32);
        if (half == 0) logitsOut[node * 32 + j] = p - m - logf(s);
    }
}

extern "C" void kernel_launch(void* const* d_in, const int* in_sizes, int n_in,
                              void* d_out, int out_size, void* d_ws, size_t ws_size,
                              hipStream_t stream) {
    const float* x   = (const float*)d_in[0];
    const int*   ei  = (const int*)d_in[1];
    const float* W1  = (const float*)d_in[2];
    const float* b1  = (const float*)d_in[3];
    const float* W2  = (const float*)d_in[4];
    const float* b2  = (const float*)d_in[5];
    const float* Wp1 = (const float*)d_in[6];
    const float* bp1 = (const float*)d_in[7];
    const float* Wp2 = (const float*)d_in[8];
    const float* bp2 = (const float*)d_in[9];

    char* ws = (char*)d_ws;
    int*    deg    = (int*)(ws + OFF_DEG);
    int*    gcnt   = (int*)(ws + OFF_GCNT);
    int*    gbase  = (int*)(ws + OFF_GBASE);
    int*    perblk = (int*)(ws + OFF_PERBLK);
    int*    erec   = (int*)(ws + OFF_EREC);
    __half* xwp    = (__half*)(ws + OFF_XW);
    __half* xw2p   = (__half*)(ws + OFF_XW2);
    float*  Wc     = (float*)(ws + OFF_WC);
    float*  bc     = (float*)(ws + OFF_BC);

    float* emb_out    = (float*)d_out;                        // [N,64]
    float* logits_out = (float*)d_out + (size_t)N_NODES * 64; // [N,32]

    zero_kernel<<<50, 256, 0, stream>>>((int4*)(ws + OFF_DEG));
    hist_kernel<<<NBLK_BIN, BIN_THREADS, 0, stream>>>(ei, deg, gcnt, perblk);
    scanP_kernel<<<1, 512, 0, stream>>>(gcnt, gbase, Wp1, bp1, Wp2, bp2, Wc, bc);
    scat_kernel<<<NBLK_BIN, BIN_THREADS, 0, stream>>>(ei, gbase, perblk, erec);

    gemm64_kernel<IN_DIM><<<(N_NODES + 255) / 256, 256, 0, stream>>>(x, W1, deg, xwp, N_NODES);
    aggA_kernel<<<NBUCK, 1024, 0, stream>>>(xwp, erec, gbase, deg, b1, W2, xw2p);
    aggB_kernel<<<NBUCK, 1024, 0, stream>>>(xw2p, erec, gbase, deg, b2, Wc, bc, emb_out, logits_out);
}

// Round 8
// 827.098 us; speedup vs baseline: 1.0096x; 1.0096x over previous
//
#include <hip/hip_runtime.h>
#include <hip/hip_fp16.h>

#define N_NODES 50000
#define N_EDGES 800000
#define IN_DIM 128
#define OUT_DIM 64
#define OUT_DATA 32

#define BUCKET_SHIFT 6
#define BUCKET_SIZE 64                                       // nodes per bucket
#define NBUCK ((N_NODES + BUCKET_SIZE - 1) / BUCKET_SIZE)    // 782
#define NBLK_BIN 128
#define BIN_THREADS 1024
#define EPB ((N_EDGES + NBLK_BIN - 1) / NBLK_BIN)            // 6250
#define AGG_THREADS 512                                      // 8 waves

// ---------------- workspace layout (bytes) ----------------
#define OFF_DEG     0u          // int[N]           -> pad 200704
#define OFF_GCNT    200704u     // int[NBUCK]       -> pad 4096
#define OFF_GBASE   204800u     // int[NBUCK+1]     -> pad 4096
#define OFF_PERBLK  208896u     // int[128*782]     -> pad 401408
#define OFF_EREC    610304u     // int[E] packed (local<<16)|src = 3.2 MB
#define OFF_XW      3810304u    // half[N*64] prescaled by dinv  = 6.4 MB
#define OFF_XW2     10210304u   // half[N*64] prescaled by dinv
#define OFF_WC      16610304u   // float[64*32]
#define OFF_BC      16618496u   // float[32]
// total ~16.6 MB

// Detect whether edge_index is stored as int64 (high dwords all zero) or int32.
__device__ __forceinline__ bool ei_is64(const int* ei) {
    int o = 0;
#pragma unroll
    for (int k = 0; k < 16; ++k) o |= ei[2 * k + 1];
    return o == 0;
}
__device__ __forceinline__ int load_ei(const int* ei, long long flat, bool is64) {
    return is64 ? (int)(((const long long*)ei)[flat]) : ei[flat];
}

// native LDS fp32 add (ds_add_f32); plain atomicAdd lowers to a CAS loop (R6: 9x slower)
__device__ __forceinline__ void ldsAdd(float* p, float v) { unsafeAtomicAdd(p, v); }

// ---------------- zero deg + gcnt (204800 B = 12800 int4) ----------------
__global__ void zero_kernel(int4* __restrict__ p) {
    int i = blockIdx.x * 256 + threadIdx.x;
    if (i < 12800) p[i] = make_int4(0, 0, 0, 0);
}

// ---------------- pass 1: bucket histogram (per-block LDS) + node degrees ----------------
__global__ __launch_bounds__(BIN_THREADS) void hist_kernel(const int* __restrict__ ei,
                                                           int* __restrict__ deg,
                                                           int* __restrict__ gcnt,
                                                           int* __restrict__ perblk) {
    __shared__ int lh[NBUCK];
    int t = threadIdx.x;
    for (int i = t; i < NBUCK; i += BIN_THREADS) lh[i] = 0;
    __syncthreads();
    bool is64 = ei_is64(ei);
    int e0 = blockIdx.x * EPB;
    int e1 = e0 + EPB; if (e1 > N_EDGES) e1 = N_EDGES;
    for (int e = e0 + t; e < e1; e += BIN_THREADS) {
        int d = load_ei(ei, (long long)N_EDGES + e, is64);
        atomicAdd(&lh[d >> BUCKET_SHIFT], 1);
        atomicAdd(&deg[d], 1);               // fire-and-forget int atomic (native)
    }
    __syncthreads();
    for (int i = t; i < NBUCK; i += BIN_THREADS)
        perblk[blockIdx.x * NBUCK + i] = atomicAdd(&gcnt[i], lh[i]);
}

// ---------------- prefix over buckets; fused head-weight folding ----------------
__global__ __launch_bounds__(1024) void scanP_kernel(
    const int* __restrict__ gcnt, int* __restrict__ gbase,
    const float* __restrict__ Wp1, const float* __restrict__ bp1,
    const float* __restrict__ Wp2, const float* __restrict__ bp2,
    float* __restrict__ Wc, float* __restrict__ bc) {
    __shared__ int tmp[1024];
    int t = threadIdx.x;
    int v = (t < NBUCK) ? gcnt[t] : 0;
    tmp[t] = v;
    __syncthreads();
    for (int o = 1; o < 1024; o <<= 1) {
        int x = tmp[t];
        if (t >= o) x += tmp[t - o];
        __syncthreads();
        tmp[t] = x;
        __syncthreads();
    }
    if (t < NBUCK) gbase[t] = tmp[t] - v;
    if (t == NBUCK - 1) gbase[NBUCK] = tmp[t];
    // head fold: Wc = Wp1@Wp2, bc = bp1@Wp2+bp2
    for (int idx = t; idx < 64 * 32; idx += 1024) {
        int r = idx >> 5, j = idx & 31;
        float s = 0.0f;
        for (int k = 0; k < 64; ++k) s += Wp1[r * 64 + k] * Wp2[k * 32 + j];
        Wc[idx] = s;
    }
    if (t < 32) {
        float s = bp2[t];
        for (int k = 0; k < 64; ++k) s += bp1[k] * Wp2[k * 32 + t];
        bc[t] = s;
    }
}

// ---------------- pass 2: scatter packed records grouped by (block,bucket) ----------------
__global__ __launch_bounds__(BIN_THREADS) void scat_kernel(const int* __restrict__ ei,
                                                           const int* __restrict__ gbase,
                                                           const int* __restrict__ perblk,
                                                           int* __restrict__ erec) {
    __shared__ int lh[NBUCK];
    __shared__ int base[NBUCK];
    int t = threadIdx.x;
    for (int i = t; i < NBUCK; i += BIN_THREADS) {
        lh[i] = 0;
        base[i] = gbase[i] + perblk[blockIdx.x * NBUCK + i];
    }
    __syncthreads();
    bool is64 = ei_is64(ei);
    int e0 = blockIdx.x * EPB;
    int e1 = e0 + EPB; if (e1 > N_EDGES) e1 = N_EDGES;
    for (int e = e0 + t; e < e1; e += BIN_THREADS) {
        int s = load_ei(ei, e, is64);
        int d = load_ei(ei, (long long)N_EDGES + e, is64);
        int b = d >> BUCKET_SHIFT;
        int slot = atomicAdd(&lh[b], 1);
        erec[base[b] + slot] = s | ((d & (BUCKET_SIZE - 1)) << 16);  // s<65536, local<64
    }
}

// ---------------- dense GEMM: Yh[row] = (X[row]@W) * dinv[row], fp16 ----------------
template <int K>
__global__ __launch_bounds__(256) void gemm64_kernel(const float* __restrict__ X,
                                                     const float* __restrict__ W,
                                                     const int* __restrict__ deg,
                                                     __half* __restrict__ Yh, int N) {
    __shared__ float Wl[K * 64];
    int t = threadIdx.x;
    for (int i = t; i < K * 16; i += 256)
        reinterpret_cast<float4*>(Wl)[i] = reinterpret_cast<const float4*>(W)[i];
    __syncthreads();
    int row = blockIdx.x * 256 + t;
    if (row >= N) return;
    float acc[64];
#pragma unroll
    for (int c = 0; c < 64; ++c) acc[c] = 0.0f;
    const float4* xr = reinterpret_cast<const float4*>(X + (size_t)row * K);
    for (int k4 = 0; k4 < K / 4; ++k4) {
        float4 xv = xr[k4];
#pragma unroll
        for (int kk = 0; kk < 4; ++kk) {
            float xs = (kk == 0) ? xv.x : (kk == 1) ? xv.y : (kk == 2) ? xv.z : xv.w;
            const float4* wr = reinterpret_cast<const float4*>(&Wl[(k4 * 4 + kk) * 64]);
#pragma unroll
            for (int c4 = 0; c4 < 16; ++c4) {
                float4 wv = wr[c4];
                acc[c4 * 4 + 0] += xs * wv.x;
                acc[c4 * 4 + 1] += xs * wv.y;
                acc[c4 * 4 + 2] += xs * wv.z;
                acc[c4 * 4 + 3] += xs * wv.w;
            }
        }
    }
    float di = rsqrtf((float)deg[row] + 1.0f);
    __half2* yr = reinterpret_cast<__half2*>(Yh + (size_t)row * 64);
#pragma unroll
    for (int c2 = 0; c2 < 32; ++c2)
        yr[c2] = __floats2half2_rn(acc[2 * c2] * di, acc[2 * c2 + 1] * di);
}

// ---------------- edge-parallel gather into LDS tile, 8 waves, unroll 8 ----------------
__device__ __forceinline__ void gather_bucket(const __half* __restrict__ xwp,
                                              const int* __restrict__ erec,
                                              float* accS, int ebeg, int eend,
                                              int wv, int lane) {
    int cnt = eend - ebeg;
    int per = (cnt + 7) >> 3;                  // 8 waves
    int b0 = ebeg + wv * per;
    int b1 = b0 + per; if (b1 > eend) b1 = eend;
    int e = b0;
    for (; e + 8 <= b1; e += 8) {
        int r0 = erec[e + 0], r1 = erec[e + 1], r2 = erec[e + 2], r3 = erec[e + 3];
        int r4 = erec[e + 4], r5 = erec[e + 5], r6 = erec[e + 6], r7 = erec[e + 7];
        float v0 = __half2float(xwp[((r0 & 0xFFFF) << 6) + lane]);
        float v1 = __half2float(xwp[((r1 & 0xFFFF) << 6) + lane]);
        float v2 = __half2float(xwp[((r2 & 0xFFFF) << 6) + lane]);
        float v3 = __half2float(xwp[((r3 & 0xFFFF) << 6) + lane]);
        float v4 = __half2float(xwp[((r4 & 0xFFFF) << 6) + lane]);
        float v5 = __half2float(xwp[((r5 & 0xFFFF) << 6) + lane]);
        float v6 = __half2float(xwp[((r6 & 0xFFFF) << 6) + lane]);
        float v7 = __half2float(xwp[((r7 & 0xFFFF) << 6) + lane]);
        ldsAdd(&accS[((r0 >> 16) << 6) + lane], v0);
        ldsAdd(&accS[((r1 >> 16) << 6) + lane], v1);
        ldsAdd(&accS[((r2 >> 16) << 6) + lane], v2);
        ldsAdd(&accS[((r3 >> 16) << 6) + lane], v3);
        ldsAdd(&accS[((r4 >> 16) << 6) + lane], v4);
        ldsAdd(&accS[((r5 >> 16) << 6) + lane], v5);
        ldsAdd(&accS[((r6 >> 16) << 6) + lane], v6);
        ldsAdd(&accS[((r7 >> 16) << 6) + lane], v7);
    }
    for (; e < b1; ++e) {
        int r = erec[e];
        ldsAdd(&accS[((r >> 16) << 6) + lane],
               __half2float(xwp[((r & 0xFFFF) << 6) + lane]));
    }
}

// ---------------- layer1: bucket agg + tanh + @W2, writes prescaled fp16 xw2 ----------------
__global__ __launch_bounds__(AGG_THREADS) void aggA_kernel(
    const __half* __restrict__ xwp, const int* __restrict__ erec,
    const int* __restrict__ gbase, const int* __restrict__ deg,
    const float* __restrict__ b1v, const float* __restrict__ W2,
    __half* __restrict__ xw2p) {
    __shared__ float accS[BUCKET_SIZE * 64];   // 16 KB
    __shared__ float W2l[64 * 64];             // 16 KB
    __shared__ float rowS[8][64];              // 2 KB
    int t = threadIdx.x, lane = t & 63, wv = t >> 6;
    for (int i = t; i < 1024; i += AGG_THREADS)
        reinterpret_cast<float4*>(W2l)[i] = reinterpret_cast<const float4*>(W2)[i];
    for (int i = t; i < BUCKET_SIZE * 64; i += AGG_THREADS) accS[i] = 0.0f;
    __syncthreads();
    int bucket = blockIdx.x;
    gather_bucket(xwp, erec, accS, gbase[bucket], gbase[bucket + 1], wv, lane);
    __syncthreads();
    int nodeBase = bucket << BUCKET_SHIFT;
#pragma unroll
    for (int k = 0; k < 8; ++k) {
        int nl = (wv << 3) + k;
        int node = nodeBase + nl;
        if (node >= N_NODES) break;
        float a = accS[(nl << 6) + lane];
        float selfv = __half2float(xwp[(node << 6) + lane]);
        float di = rsqrtf((float)deg[node] + 1.0f);
        float h = tanhf((a + selfv) * di + b1v[lane]);
        rowS[wv][lane] = h;                    // wave-private
        float o = 0.0f;
#pragma unroll
        for (int f4 = 0; f4 < 16; ++f4) {
            float4 rv = reinterpret_cast<const float4*>(&rowS[wv][0])[f4];
            o += rv.x * W2l[(f4 * 4 + 0) * 64 + lane];
            o += rv.y * W2l[(f4 * 4 + 1) * 64 + lane];
            o += rv.z * W2l[(f4 * 4 + 2) * 64 + lane];
            o += rv.w * W2l[(f4 * 4 + 3) * 64 + lane];
        }
        xw2p[(node << 6) + lane] = __float2half_rn(o * di);   // prescale for layer 2
    }
}

// ---------------- layer2: bucket agg + emb + tanh + head + log_softmax ----------------
__global__ __launch_bounds__(AGG_THREADS) void aggB_kernel(
    const __half* __restrict__ xw2p, const int* __restrict__ erec,
    const int* __restrict__ gbase, const int* __restrict__ deg,
    const float* __restrict__ b2v, const float* __restrict__ Wc,
    const float* __restrict__ bc, float* __restrict__ embOut,
    float* __restrict__ logitsOut) {
    __shared__ float accS[BUCKET_SIZE * 64];   // 16 KB
    __shared__ float Wcl[64 * 32];             // 8 KB
    __shared__ float rowS[8][64];              // 2 KB
    __shared__ float bcl[32];
    int t = threadIdx.x, lane = t & 63, wv = t >> 6;
    if (t < 512) reinterpret_cast<float4*>(Wcl)[t] = reinterpret_cast<const float4*>(Wc)[t];
    if (t < 32) bcl[t] = bc[t];
    for (int i = t; i < BUCKET_SIZE * 64; i += AGG_THREADS) accS[i] = 0.0f;
    __syncthreads();
    int bucket = blockIdx.x;
    gather_bucket(xw2p, erec, accS, gbase[bucket], gbase[bucket + 1], wv, lane);
    __syncthreads();
    int nodeBase = bucket << BUCKET_SHIFT;
#pragma unroll
    for (int k = 0; k < 8; ++k) {
        int nl = (wv << 3) + k;
        int node = nodeBase + nl;
        if (node >= N_NODES) break;
        float a = accS[(nl << 6) + lane];
        float selfv = __half2float(xw2p[(node << 6) + lane]);
        float di = rsqrtf((float)deg[node] + 1.0f);
        float v = (a + selfv) * di + b2v[lane];
        embOut[(node << 6) + lane] = v;
        rowS[wv][lane] = tanhf(v);             // wave-private
        int j = lane & 31, half = lane >> 5;
        float p = half ? 0.0f : bcl[j];
#pragma unroll
        for (int f4 = 0; f4 < 8; ++f4) {
            float4 rv = reinterpret_cast<const float4*>(&rowS[wv][half * 32])[f4];
            int fb = half * 32 + f4 * 4;
            p += rv.x * Wcl[(fb + 0) * 32 + j];
            p += rv.y * Wcl[(fb + 1) * 32 + j];
            p += rv.z * Wcl[(fb + 2) * 32 + j];
            p += rv.w * Wcl[(fb + 3) * 32 + j];
        }
        p += __shfl_down(p, 32);               // lanes 0..31 hold full logits
        float m = p;
#pragma unroll
        for (int o = 16; o > 0; o >>= 1) m = fmaxf(m, __shfl_xor(m, o, 32));
        float ex = __expf(p - m);
        float s = ex;
#pragma unroll
        for (int o = 16; o > 0; o >>= 1) s += __shfl_xor(s, o, 32);
        if (half == 0) logitsOut[node * 32 + j] = p - m - logf(s);
    }
}

extern "C" void kernel_launch(void* const* d_in, const int* in_sizes, int n_in,
                              void* d_out, int out_size, void* d_ws, size_t ws_size,
                              hipStream_t stream) {
    const float* x   = (const float*)d_in[0];
    const int*   ei  = (const int*)d_in[1];
    const float* W1  = (const float*)d_in[2];
    const float* b1  = (const float*)d_in[3];
    const float* W2  = (const float*)d_in[4];
    const float* b2  = (const float*)d_in[5];
    const float* Wp1 = (const float*)d_in[6];
    const float* bp1 = (const float*)d_in[7];
    const float* Wp2 = (const float*)d_in[8];
    const float* bp2 = (const float*)d_in[9];

    char* ws = (char*)d_ws;
    int*    deg    = (int*)(ws + OFF_DEG);
    int*    gcnt   = (int*)(ws + OFF_GCNT);
    int*    gbase  = (int*)(ws + OFF_GBASE);
    int*    perblk = (int*)(ws + OFF_PERBLK);
    int*    erec   = (int*)(ws + OFF_EREC);
    __half* xwp    = (__half*)(ws + OFF_XW);
    __half* xw2p   = (__half*)(ws + OFF_XW2);
    float*  Wc     = (float*)(ws + OFF_WC);
    float*  bc     = (float*)(ws + OFF_BC);

    float* emb_out    = (float*)d_out;                        // [N,64]
    float* logits_out = (float*)d_out + (size_t)N_NODES * 64; // [N,32]

    zero_kernel<<<50, 256, 0, stream>>>((int4*)(ws + OFF_DEG));
    hist_kernel<<<NBLK_BIN, BIN_THREADS, 0, stream>>>(ei, deg, gcnt, perblk);
    scanP_kernel<<<1, 1024, 0, stream>>>(gcnt, gbase, Wp1, bp1, Wp2, bp2, Wc, bc);
    scat_kernel<<<NBLK_BIN, BIN_THREADS, 0, stream>>>(ei, gbase, perblk, erec);

    gemm64_kernel<IN_DIM><<<(N_NODES + 255) / 256, 256, 0, stream>>>(x, W1, deg, xwp, N_NODES);
    aggA_kernel<<<NBUCK, AGG_THREADS, 0, stream>>>(xwp, erec, gbase, deg, b1, W2, xw2p);
    aggB_kernel<<<NBUCK, AGG_THREADS, 0, stream>>>(xw2p, erec, gbase, deg, b2, Wc, bc, emb_out, logits_out);
}

// Round 9
// 190.560 us; speedup vs baseline: 4.3821x; 4.3404x over previous
//
#include <hip/hip_runtime.h>
#include <hip/hip_fp16.h>

#define N_NODES 50000
#define N_EDGES 800000
#define IN_DIM 128
#define OUT_DIM 64
#define OUT_DATA 32

#define BUCKET_SHIFT 6
#define BUCKET_SIZE 64                                       // nodes per bucket
#define NBUCK ((N_NODES + BUCKET_SIZE - 1) / BUCKET_SIZE)    // 782
#define NBLK_BIN 128
#define BIN_THREADS 1024
#define EPB ((N_EDGES + NBLK_BIN - 1) / NBLK_BIN)            // 6250
#define AGG_THREADS 512                                      // 8 waves
#define ELCAP 1536                                           // bucket edge capacity (mean 1024, 15 sigma)

// ---------------- workspace layout (bytes) ----------------
#define OFF_DEG     0u          // int[N]           -> pad 200704
#define OFF_GCNT    200704u     // int[NBUCK]       -> pad 4096
#define OFF_GBASE   204800u     // int[NBUCK+1]     -> pad 4096
#define OFF_PERBLK  208896u     // int[128*782]     -> pad 401408
#define OFF_EREC    610304u     // int[E] packed (local<<16)|src = 3.2 MB
#define OFF_XW      3810304u    // half[N*64] prescaled by dinv  = 6.4 MB
#define OFF_XW2     10210304u   // half[N*64] prescaled by dinv
#define OFF_WC      16610304u   // float[64*32]
#define OFF_BC      16618496u   // float[32]
// total ~16.6 MB

// Detect whether edge_index is stored as int64 (high dwords all zero) or int32.
__device__ __forceinline__ bool ei_is64(const int* ei) {
    int o = 0;
#pragma unroll
    for (int k = 0; k < 16; ++k) o |= ei[2 * k + 1];
    return o == 0;
}
__device__ __forceinline__ int load_ei(const int* ei, long long flat, bool is64) {
    return is64 ? (int)(((const long long*)ei)[flat]) : ei[flat];
}

// ---------------- zero deg + gcnt (204800 B = 12800 int4) ----------------
__global__ void zero_kernel(int4* __restrict__ p) {
    int i = blockIdx.x * 256 + threadIdx.x;
    if (i < 12800) p[i] = make_int4(0, 0, 0, 0);
}

// ---------------- pass 1: bucket histogram (per-block LDS) + node degrees ----------------
__global__ __launch_bounds__(BIN_THREADS) void hist_kernel(const int* __restrict__ ei,
                                                           int* __restrict__ deg,
                                                           int* __restrict__ gcnt,
                                                           int* __restrict__ perblk) {
    __shared__ int lh[NBUCK];
    int t = threadIdx.x;
    for (int i = t; i < NBUCK; i += BIN_THREADS) lh[i] = 0;
    __syncthreads();
    bool is64 = ei_is64(ei);
    int e0 = blockIdx.x * EPB;
    int e1 = e0 + EPB; if (e1 > N_EDGES) e1 = N_EDGES;
    for (int e = e0 + t; e < e1; e += BIN_THREADS) {
        int d = load_ei(ei, (long long)N_EDGES + e, is64);
        atomicAdd(&lh[d >> BUCKET_SHIFT], 1);
        atomicAdd(&deg[d], 1);               // fire-and-forget int atomic (native)
    }
    __syncthreads();
    for (int i = t; i < NBUCK; i += BIN_THREADS)
        perblk[blockIdx.x * NBUCK + i] = atomicAdd(&gcnt[i], lh[i]);
}

// ---------------- prefix over buckets; fused head-weight folding ----------------
__global__ __launch_bounds__(1024) void scanP_kernel(
    const int* __restrict__ gcnt, int* __restrict__ gbase,
    const float* __restrict__ Wp1, const float* __restrict__ bp1,
    const float* __restrict__ Wp2, const float* __restrict__ bp2,
    float* __restrict__ Wc, float* __restrict__ bc) {
    __shared__ int tmp[1024];
    int t = threadIdx.x;
    int v = (t < NBUCK) ? gcnt[t] : 0;
    tmp[t] = v;
    __syncthreads();
    for (int o = 1; o < 1024; o <<= 1) {
        int x = tmp[t];
        if (t >= o) x += tmp[t - o];
        __syncthreads();
        tmp[t] = x;
        __syncthreads();
    }
    if (t < NBUCK) gbase[t] = tmp[t] - v;
    if (t == NBUCK - 1) gbase[NBUCK] = tmp[t];
    // head fold: Wc = Wp1@Wp2, bc = bp1@Wp2+bp2
    for (int idx = t; idx < 64 * 32; idx += 1024) {
        int r = idx >> 5, j = idx & 31;
        float s = 0.0f;
        for (int k = 0; k < 64; ++k) s += Wp1[r * 64 + k] * Wp2[k * 32 + j];
        Wc[idx] = s;
    }
    if (t < 32) {
        float s = bp2[t];
        for (int k = 0; k < 64; ++k) s += bp1[k] * Wp2[k * 32 + t];
        bc[t] = s;
    }
}

// ---------------- pass 2: scatter packed records grouped by (block,bucket) ----------------
__global__ __launch_bounds__(BIN_THREADS) void scat_kernel(const int* __restrict__ ei,
                                                           const int* __restrict__ gbase,
                                                           const int* __restrict__ perblk,
                                                           int* __restrict__ erec) {
    __shared__ int lh[NBUCK];
    __shared__ int base[NBUCK];
    int t = threadIdx.x;
    for (int i = t; i < NBUCK; i += BIN_THREADS) {
        lh[i] = 0;
        base[i] = gbase[i] + perblk[blockIdx.x * NBUCK + i];
    }
    __syncthreads();
    bool is64 = ei_is64(ei);
    int e0 = blockIdx.x * EPB;
    int e1 = e0 + EPB; if (e1 > N_EDGES) e1 = N_EDGES;
    for (int e = e0 + t; e < e1; e += BIN_THREADS) {
        int s = load_ei(ei, e, is64);
        int d = load_ei(ei, (long long)N_EDGES + e, is64);
        int b = d >> BUCKET_SHIFT;
        int slot = atomicAdd(&lh[b], 1);
        erec[base[b] + slot] = s | ((d & (BUCKET_SIZE - 1)) << 16);  // s<65536, local<64
    }
}

// ---------------- dense GEMM: Yh[row] = (X[row]@W) * dinv[row], fp16 ----------------
template <int K>
__global__ __launch_bounds__(256) void gemm64_kernel(const float* __restrict__ X,
                                                     const float* __restrict__ W,
                                                     const int* __restrict__ deg,
                                                     __half* __restrict__ Yh, int N) {
    __shared__ float Wl[K * 64];
    int t = threadIdx.x;
    for (int i = t; i < K * 16; i += 256)
        reinterpret_cast<float4*>(Wl)[i] = reinterpret_cast<const float4*>(W)[i];
    __syncthreads();
    int row = blockIdx.x * 256 + t;
    if (row >= N) return;
    float acc[64];
#pragma unroll
    for (int c = 0; c < 64; ++c) acc[c] = 0.0f;
    const float4* xr = reinterpret_cast<const float4*>(X + (size_t)row * K);
    for (int k4 = 0; k4 < K / 4; ++k4) {
        float4 xv = xr[k4];
#pragma unroll
        for (int kk = 0; kk < 4; ++kk) {
            float xs = (kk == 0) ? xv.x : (kk == 1) ? xv.y : (kk == 2) ? xv.z : xv.w;
            const float4* wr = reinterpret_cast<const float4*>(&Wl[(k4 * 4 + kk) * 64]);
#pragma unroll
            for (int c4 = 0; c4 < 16; ++c4) {
                float4 wv = wr[c4];
                acc[c4 * 4 + 0] += xs * wv.x;
                acc[c4 * 4 + 1] += xs * wv.y;
                acc[c4 * 4 + 2] += xs * wv.z;
                acc[c4 * 4 + 3] += xs * wv.w;
            }
        }
    }
    float di = rsqrtf((float)deg[row] + 1.0f);
    __half2* yr = reinterpret_cast<__half2*>(Yh + (size_t)row * 64);
#pragma unroll
    for (int c2 = 0; c2 < 32; ++c2)
        yr[c2] = __floats2half2_rn(acc[2 * c2] * di, acc[2 * c2 + 1] * di);
}

// ============ in-bucket CSR sort (LDS) + atomic-free run accumulation ============
// After sort, wave wv owns locals [8wv, 8wv+8) = contiguous edge range; each local
// is one contiguous run -> accumulate in a register, single plain ds_write per local.
__device__ __forceinline__ void gather_runs(const __half* __restrict__ xwp,
                                            const int* __restrict__ elist2,
                                            const int* __restrict__ startS,
                                            float* __restrict__ accS,
                                            int wv, int lane) {
    int lo = startS[wv * 8];
    int hi = startS[wv * 8 + 8];
    int cur = -1;
    float racc = 0.0f;
#define PROC1(RR, VV) { int _l = (RR) >> 16; \
    if (_l != cur) { if (cur >= 0) accS[(cur << 6) + lane] = racc; cur = _l; racc = 0.0f; } \
    racc += (VV); }
    int e = lo;
    for (; e + 8 <= hi; e += 8) {
        int r0 = elist2[e + 0], r1 = elist2[e + 1], r2 = elist2[e + 2], r3 = elist2[e + 3];
        int r4 = elist2[e + 4], r5 = elist2[e + 5], r6 = elist2[e + 6], r7 = elist2[e + 7];
        float v0 = __half2float(xwp[((r0 & 0xFFFF) << 6) + lane]);
        float v1 = __half2float(xwp[((r1 & 0xFFFF) << 6) + lane]);
        float v2 = __half2float(xwp[((r2 & 0xFFFF) << 6) + lane]);
        float v3 = __half2float(xwp[((r3 & 0xFFFF) << 6) + lane]);
        float v4 = __half2float(xwp[((r4 & 0xFFFF) << 6) + lane]);
        float v5 = __half2float(xwp[((r5 & 0xFFFF) << 6) + lane]);
        float v6 = __half2float(xwp[((r6 & 0xFFFF) << 6) + lane]);
        float v7 = __half2float(xwp[((r7 & 0xFFFF) << 6) + lane]);
        PROC1(r0, v0); PROC1(r1, v1); PROC1(r2, v2); PROC1(r3, v3);
        PROC1(r4, v4); PROC1(r5, v5); PROC1(r6, v6); PROC1(r7, v7);
    }
    for (; e < hi; ++e) {
        int r = elist2[e];
        float v = __half2float(xwp[((r & 0xFFFF) << 6) + lane]);
        PROC1(r, v);
    }
    if (cur >= 0) accS[(cur << 6) + lane] = racc;
#undef PROC1
}

// Shared preamble for both agg kernels: load+sort bucket edges, fill accS.
// Phases: load elist / zero -> hist(rank) -> scan(wave0) -> scatter -> runs.
#define AGG_SORT_AND_GATHER(SRC)                                                     \
    int t = threadIdx.x, lane = t & 63, wv = t >> 6;                                 \
    int ebeg = gbase[blockIdx.x], eend = gbase[blockIdx.x + 1];                      \
    int ecnt = eend - ebeg; if (ecnt > ELCAP) ecnt = ELCAP;                          \
    for (int i = t; i < ecnt; i += AGG_THREADS) elist[i] = erec[ebeg + i];           \
    for (int i = t; i < BUCKET_SIZE * 64; i += AGG_THREADS) accS[i] = 0.0f;          \
    if (t < 64) lcntS[t] = 0;                                                        \
    __syncthreads();                                                                 \
    int rec0 = -1, rank0 = 0, rec1 = -1, rank1 = 0, rec2 = -1, rank2 = 0;            \
    { int i = t;        if (i < ecnt) { rec0 = elist[i]; rank0 = atomicAdd(&lcntS[rec0 >> 16], 1); } } \
    { int i = t + 512;  if (i < ecnt) { rec1 = elist[i]; rank1 = atomicAdd(&lcntS[rec1 >> 16], 1); } } \
    { int i = t + 1024; if (i < ecnt) { rec2 = elist[i]; rank2 = atomicAdd(&lcntS[rec2 >> 16], 1); } } \
    __syncthreads();                                                                 \
    if (t < 64) {                                                                    \
        int vcnt = lcntS[t]; int sum = vcnt;                                         \
        for (int off = 1; off < 64; off <<= 1) {                                     \
            int o = __shfl_up(sum, off, 64);                                         \
            if (t >= off) sum += o;                                                  \
        }                                                                            \
        startS[t + 1] = sum; if (t == 0) startS[0] = 0;                              \
    }                                                                                \
    __syncthreads();                                                                 \
    if (rec0 >= 0) elist2[startS[rec0 >> 16] + rank0] = rec0;                        \
    if (rec1 >= 0) elist2[startS[rec1 >> 16] + rank1] = rec1;                        \
    if (rec2 >= 0) elist2[startS[rec2 >> 16] + rank2] = rec2;                        \
    __syncthreads();                                                                 \
    gather_runs(SRC, elist2, startS, accS, wv, lane);                                \
    __syncthreads();

// ---------------- layer1: bucket agg + tanh + @W2, writes prescaled fp16 xw2 ----------------
__global__ __launch_bounds__(AGG_THREADS) void aggA_kernel(
    const __half* __restrict__ xwp, const int* __restrict__ erec,
    const int* __restrict__ gbase, const int* __restrict__ deg,
    const float* __restrict__ b1v, const float* __restrict__ W2,
    __half* __restrict__ xw2p) {
    __shared__ int elist[ELCAP];               // 6 KB
    __shared__ int elist2[ELCAP];              // 6 KB
    __shared__ float accS[BUCKET_SIZE * 64];   // 16 KB
    __shared__ float W2l[64 * 64];             // 16 KB
    __shared__ float rowS[8][64];              // 2 KB
    __shared__ int lcntS[64];
    __shared__ int startS[65];
    {
        int tt = threadIdx.x;
        for (int i = tt; i < 1024; i += AGG_THREADS)
            reinterpret_cast<float4*>(W2l)[i] = reinterpret_cast<const float4*>(W2)[i];
    }
    AGG_SORT_AND_GATHER(xwp)
    int nodeBase = blockIdx.x << BUCKET_SHIFT;
#pragma unroll
    for (int k = 0; k < 8; ++k) {
        int nl = (wv << 3) + k;
        int node = nodeBase + nl;
        if (node >= N_NODES) break;
        float a = accS[(nl << 6) + lane];
        float selfv = __half2float(xwp[(node << 6) + lane]);
        float di = rsqrtf((float)deg[node] + 1.0f);
        float h = tanhf((a + selfv) * di + b1v[lane]);
        rowS[wv][lane] = h;                    // wave-private
        float o = 0.0f;
#pragma unroll
        for (int f4 = 0; f4 < 16; ++f4) {
            float4 rv = reinterpret_cast<const float4*>(&rowS[wv][0])[f4];
            o += rv.x * W2l[(f4 * 4 + 0) * 64 + lane];
            o += rv.y * W2l[(f4 * 4 + 1) * 64 + lane];
            o += rv.z * W2l[(f4 * 4 + 2) * 64 + lane];
            o += rv.w * W2l[(f4 * 4 + 3) * 64 + lane];
        }
        xw2p[(node << 6) + lane] = __float2half_rn(o * di);   // prescale for layer 2
    }
}

// ---------------- layer2: bucket agg + emb + tanh + head + log_softmax ----------------
__global__ __launch_bounds__(AGG_THREADS) void aggB_kernel(
    const __half* __restrict__ xw2p, const int* __restrict__ erec,
    const int* __restrict__ gbase, const int* __restrict__ deg,
    const float* __restrict__ b2v, const float* __restrict__ Wc,
    const float* __restrict__ bc, float* __restrict__ embOut,
    float* __restrict__ logitsOut) {
    __shared__ int elist[ELCAP];               // 6 KB
    __shared__ int elist2[ELCAP];              // 6 KB
    __shared__ float accS[BUCKET_SIZE * 64];   // 16 KB
    __shared__ float Wcl[64 * 32];             // 8 KB
    __shared__ float rowS[8][64];              // 2 KB
    __shared__ float bcl[32];
    __shared__ int lcntS[64];
    __shared__ int startS[65];
    {
        int tt = threadIdx.x;
        if (tt < 512) reinterpret_cast<float4*>(Wcl)[tt] = reinterpret_cast<const float4*>(Wc)[tt];
        if (tt < 32) bcl[tt] = bc[tt];
    }
    AGG_SORT_AND_GATHER(xw2p)
    int nodeBase = blockIdx.x << BUCKET_SHIFT;
#pragma unroll
    for (int k = 0; k < 8; ++k) {
        int nl = (wv << 3) + k;
        int node = nodeBase + nl;
        if (node >= N_NODES) break;
        float a = accS[(nl << 6) + lane];
        float selfv = __half2float(xw2p[(node << 6) + lane]);
        float di = rsqrtf((float)deg[node] + 1.0f);
        float v = (a + selfv) * di + b2v[lane];
        embOut[(node << 6) + lane] = v;
        rowS[wv][lane] = tanhf(v);             // wave-private
        int j = lane & 31, half = lane >> 5;
        float p = half ? 0.0f : bcl[j];
#pragma unroll
        for (int f4 = 0; f4 < 8; ++f4) {
            float4 rv = reinterpret_cast<const float4*>(&rowS[wv][half * 32])[f4];
            int fb = half * 32 + f4 * 4;
            p += rv.x * Wcl[(fb + 0) * 32 + j];
            p += rv.y * Wcl[(fb + 1) * 32 + j];
            p += rv.z * Wcl[(fb + 2) * 32 + j];
            p += rv.w * Wcl[(fb + 3) * 32 + j];
        }
        p += __shfl_down(p, 32);               // lanes 0..31 hold full logits
        float m = p;
#pragma unroll
        for (int o = 16; o > 0; o >>= 1) m = fmaxf(m, __shfl_xor(m, o, 32));
        float ex = __expf(p - m);
        float s = ex;
#pragma unroll
        for (int o = 16; o > 0; o >>= 1) s += __shfl_xor(s, o, 32);
        if (half == 0) logitsOut[node * 32 + j] = p - m - logf(s);
    }
}

extern "C" void kernel_launch(void* const* d_in, const int* in_sizes, int n_in,
                              void* d_out, int out_size, void* d_ws, size_t ws_size,
                              hipStream_t stream) {
    const float* x   = (const float*)d_in[0];
    const int*   ei  = (const int*)d_in[1];
    const float* W1  = (const float*)d_in[2];
    const float* b1  = (const float*)d_in[3];
    const float* W2  = (const float*)d_in[4];
    const float* b2  = (const float*)d_in[5];
    const float* Wp1 = (const float*)d_in[6];
    const float* bp1 = (const float*)d_in[7];
    const float* Wp2 = (const float*)d_in[8];
    const float* bp2 = (const float*)d_in[9];

    char* ws = (char*)d_ws;
    int*    deg    = (int*)(ws + OFF_DEG);
    int*    gcnt   = (int*)(ws + OFF_GCNT);
    int*    gbase  = (int*)(ws + OFF_GBASE);
    int*    perblk = (int*)(ws + OFF_PERBLK);
    int*    erec   = (int*)(ws + OFF_EREC);
    __half* xwp    = (__half*)(ws + OFF_XW);
    __half* xw2p   = (__half*)(ws + OFF_XW2);
    float*  Wc     = (float*)(ws + OFF_WC);
    float*  bc     = (float*)(ws + OFF_BC);

    float* emb_out    = (float*)d_out;                        // [N,64]
    float* logits_out = (float*)d_out + (size_t)N_NODES * 64; // [N,32]

    zero_kernel<<<50, 256, 0, stream>>>((int4*)(ws + OFF_DEG));
    hist_kernel<<<NBLK_BIN, BIN_THREADS, 0, stream>>>(ei, deg, gcnt, perblk);
    scanP_kernel<<<1, 1024, 0, stream>>>(gcnt, gbase, Wp1, bp1, Wp2, bp2, Wc, bc);
    scat_kernel<<<NBLK_BIN, BIN_THREADS, 0, stream>>>(ei, gbase, perblk, erec);

    gemm64_kernel<IN_DIM><<<(N_NODES + 255) / 256, 256, 0, stream>>>(x, W1, deg, xwp, N_NODES);
    aggA_kernel<<<NBUCK, AGG_THREADS, 0, stream>>>(xwp, erec, gbase, deg, b1, W2, xw2p);
    aggB_kernel<<<NBUCK, AGG_THREADS, 0, stream>>>(xw2p, erec, gbase, deg, b2, Wc, bc, emb_out, logits_out);
}

// Round 11
// 141.693 us; speedup vs baseline: 5.8934x; 1.3449x over previous
//
#include <hip/hip_runtime.h>
#include <hip/hip_fp16.h>

#define N_NODES 50000
#define N_EDGES 800000
#define IN_DIM 128
#define OUT_DIM 64
#define OUT_DATA 32

#define BUCKET_SHIFT 6
#define BUCKET_SIZE 64                                       // nodes per bucket
#define NBUCK ((N_NODES + BUCKET_SIZE - 1) / BUCKET_SIZE)    // 782
#define NBLK_BIN 128
#define BIN_THREADS 1024
#define EPB ((N_EDGES + NBLK_BIN - 1) / NBLK_BIN)            // 6250
#define ELCAP 1536                                           // bucket edge capacity (mean 1024)

// ---------------- workspace layout (bytes) ----------------
#define OFF_GCNT    0u          // int[NBUCK]       -> pad 4096  (zeroed)
#define OFF_GBASE   4096u       // int[NBUCK+1]     -> pad 4096
#define OFF_DEG     8192u       // int[50048]       -> pad 200704 (written by sortK)
#define OFF_NSTART  208896u     // int[50048]       -> pad 200704 (written by sortK)
#define OFF_PERBLK  409600u     // int[128*782]     -> pad 401408
#define OFF_EREC    811008u     // int[E] packed (local<<16)|src = 3.2 MB
#define OFF_EREC2   4012032u    // int[E] node-grouped           = 3.2 MB
#define OFF_XW      7213056u    // half[N*64] prescaled by dinv  = 6.4 MB
#define OFF_XW2     13613056u   // half[N*64] prescaled by dinv
#define OFF_WC      20013056u   // float[64*32]
#define OFF_BC      20021248u   // float[32]
// total ~20 MB

// Detect whether edge_index is stored as int64 (high dwords all zero) or int32.
__device__ __forceinline__ bool ei_is64(const int* ei) {
    int o = 0;
#pragma unroll
    for (int k = 0; k < 16; ++k) o |= ei[2 * k + 1];
    return o == 0;
}
__device__ __forceinline__ int load_ei(const int* ei, long long flat, bool is64) {
    return is64 ? (int)(((const long long*)ei)[flat]) : ei[flat];
}

// ---------------- zero gcnt (4096 B = 256 int4) ----------------
__global__ void zero_kernel(int4* __restrict__ p) {
    p[threadIdx.x] = make_int4(0, 0, 0, 0);
}

// ---------------- pass 1: bucket histogram (per-block LDS) ----------------
__global__ __launch_bounds__(BIN_THREADS) void hist_kernel(const int* __restrict__ ei,
                                                           int* __restrict__ gcnt,
                                                           int* __restrict__ perblk) {
    __shared__ int lh[NBUCK];
    int t = threadIdx.x;
    for (int i = t; i < NBUCK; i += BIN_THREADS) lh[i] = 0;
    __syncthreads();
    bool is64 = ei_is64(ei);
    int e0 = blockIdx.x * EPB;
    int e1 = e0 + EPB; if (e1 > N_EDGES) e1 = N_EDGES;
    for (int e = e0 + t; e < e1; e += BIN_THREADS) {
        int d = load_ei(ei, (long long)N_EDGES + e, is64);
        atomicAdd(&lh[d >> BUCKET_SHIFT], 1);
    }
    __syncthreads();
    for (int i = t; i < NBUCK; i += BIN_THREADS)
        perblk[blockIdx.x * NBUCK + i] = atomicAdd(&gcnt[i], lh[i]);
}

// ---------------- prefix over buckets; fused head-weight folding ----------------
__global__ __launch_bounds__(1024) void scanP_kernel(
    const int* __restrict__ gcnt, int* __restrict__ gbase,
    const float* __restrict__ Wp1, const float* __restrict__ bp1,
    const float* __restrict__ Wp2, const float* __restrict__ bp2,
    float* __restrict__ Wc, float* __restrict__ bc) {
    __shared__ int tmp[1024];
    int t = threadIdx.x;
    int v = (t < NBUCK) ? gcnt[t] : 0;
    tmp[t] = v;
    __syncthreads();
    for (int o = 1; o < 1024; o <<= 1) {
        int x = tmp[t];
        if (t >= o) x += tmp[t - o];
        __syncthreads();
        tmp[t] = x;
        __syncthreads();
    }
    if (t < NBUCK) gbase[t] = tmp[t] - v;
    if (t == NBUCK - 1) gbase[NBUCK] = tmp[t];
    // head fold: Wc = Wp1@Wp2, bc = bp1@Wp2+bp2
    for (int idx = t; idx < 64 * 32; idx += 1024) {
        int r = idx >> 5, j = idx & 31;
        float s = 0.0f;
        for (int k = 0; k < 64; ++k) s += Wp1[r * 64 + k] * Wp2[k * 32 + j];
        Wc[idx] = s;
    }
    if (t < 32) {
        float s = bp2[t];
        for (int k = 0; k < 64; ++k) s += bp1[k] * Wp2[k * 32 + t];
        bc[t] = s;
    }
}

// ---------------- pass 2: scatter packed records grouped by (block,bucket) ----------------
__global__ __launch_bounds__(BIN_THREADS) void scat_kernel(const int* __restrict__ ei,
                                                           const int* __restrict__ gbase,
                                                           const int* __restrict__ perblk,
                                                           int* __restrict__ erec) {
    __shared__ int lh[NBUCK];
    __shared__ int base[NBUCK];
    int t = threadIdx.x;
    for (int i = t; i < NBUCK; i += BIN_THREADS) {
        lh[i] = 0;
        base[i] = gbase[i] + perblk[blockIdx.x * NBUCK + i];
    }
    __syncthreads();
    bool is64 = ei_is64(ei);
    int e0 = blockIdx.x * EPB;
    int e1 = e0 + EPB; if (e1 > N_EDGES) e1 = N_EDGES;
    for (int e = e0 + t; e < e1; e += BIN_THREADS) {
        int s = load_ei(ei, e, is64);
        int d = load_ei(ei, (long long)N_EDGES + e, is64);
        int b = d >> BUCKET_SHIFT;
        int slot = atomicAdd(&lh[b], 1);
        erec[base[b] + slot] = s | ((d & (BUCKET_SIZE - 1)) << 16);  // s<65536, local<64
    }
}

// ---------------- one-time in-bucket counting sort: erec -> node-grouped erec2 ----------------
// Also emits nodeStart[] and deg[] (scan diffs) so aggs are pure gathers.
__global__ __launch_bounds__(512) void sortK_kernel(const int* __restrict__ erec,
                                                    const int* __restrict__ gbase,
                                                    int* __restrict__ erec2,
                                                    int* __restrict__ nodeStart,
                                                    int* __restrict__ deg) {
    __shared__ int elist[ELCAP];
    __shared__ int lcntS[64];
    __shared__ int startS[65];
    int t = threadIdx.x;
    int ebeg = gbase[blockIdx.x], eend = gbase[blockIdx.x + 1];
    int ecnt = eend - ebeg; if (ecnt > ELCAP) ecnt = ELCAP;
    for (int i = t; i < ecnt; i += 512) elist[i] = erec[ebeg + i];
    if (t < 64) lcntS[t] = 0;
    __syncthreads();
    int rec0 = -1, rank0 = 0, rec1 = -1, rank1 = 0, rec2 = -1, rank2 = 0;
    { int i = t;        if (i < ecnt) { rec0 = elist[i]; rank0 = atomicAdd(&lcntS[rec0 >> 16], 1); } }
    { int i = t + 512;  if (i < ecnt) { rec1 = elist[i]; rank1 = atomicAdd(&lcntS[rec1 >> 16], 1); } }
    { int i = t + 1024; if (i < ecnt) { rec2 = elist[i]; rank2 = atomicAdd(&lcntS[rec2 >> 16], 1); } }
    __syncthreads();
    if (t < 64) {
        int vcnt = lcntS[t]; int sum = vcnt;
        for (int off = 1; off < 64; off <<= 1) {
            int o = __shfl_up(sum, off, 64);
            if (t >= off) sum += o;
        }
        startS[t + 1] = sum; if (t == 0) startS[0] = 0;
    }
    __syncthreads();
    if (rec0 >= 0) erec2[ebeg + startS[rec0 >> 16] + rank0] = rec0;
    if (rec1 >= 0) erec2[ebeg + startS[rec1 >> 16] + rank1] = rec1;
    if (rec2 >= 0) erec2[ebeg + startS[rec2 >> 16] + rank2] = rec2;
    if (t < 64) {
        int node = (blockIdx.x << BUCKET_SHIFT) + t;
        nodeStart[node] = ebeg + startS[t];
        deg[node] = startS[t + 1] - startS[t];
    }
}

// ---------------- dense GEMM: Yh[row] = (X[row]@W) * dinv[row], fp16 ----------------
template <int K>
__global__ __launch_bounds__(256) void gemm64_kernel(const float* __restrict__ X,
                                                     const float* __restrict__ W,
                                                     const int* __restrict__ deg,
                                                     __half* __restrict__ Yh, int N) {
    __shared__ float Wl[K * 64];
    int t = threadIdx.x;
    for (int i = t; i < K * 16; i += 256)
        reinterpret_cast<float4*>(Wl)[i] = reinterpret_cast<const float4*>(W)[i];
    __syncthreads();
    int row = blockIdx.x * 256 + t;
    if (row >= N) return;
    float acc[64];
#pragma unroll
    for (int c = 0; c < 64; ++c) acc[c] = 0.0f;
    const float4* xr = reinterpret_cast<const float4*>(X + (size_t)row * K);
    for (int k4 = 0; k4 < K / 4; ++k4) {
        float4 xv = xr[k4];
#pragma unroll
        for (int kk = 0; kk < 4; ++kk) {
            float xs = (kk == 0) ? xv.x : (kk == 1) ? xv.y : (kk == 2) ? xv.z : xv.w;
            const float4* wr = reinterpret_cast<const float4*>(&Wl[(k4 * 4 + kk) * 64]);
#pragma unroll
            for (int c4 = 0; c4 < 16; ++c4) {
                float4 wv = wr[c4];
                acc[c4 * 4 + 0] += xs * wv.x;
                acc[c4 * 4 + 1] += xs * wv.y;
                acc[c4 * 4 + 2] += xs * wv.z;
                acc[c4 * 4 + 3] += xs * wv.w;
            }
        }
    }
    float di = rsqrtf((float)deg[row] + 1.0f);
    __half2* yr = reinterpret_cast<__half2*>(Yh + (size_t)row * 64);
#pragma unroll
    for (int c2 = 0; c2 < 32; ++c2)
        yr[c2] = __floats2half2_rn(acc[2 * c2] * di, acc[2 * c2 + 1] * di);
}

// ---------------- per-node register gather, 16 rows in flight ----------------
__device__ __forceinline__ float gatherN(const __half* __restrict__ xwp,
                                         const int* __restrict__ er,
                                         int s0, int n, int lane) {
    float acc = 0.0f;
    int e = 0;
    for (; e + 16 <= n; e += 16) {
        int r[16];
#pragma unroll
        for (int k = 0; k < 16; ++k) r[k] = er[s0 + e + k];
        float v[16];
#pragma unroll
        for (int k = 0; k < 16; ++k) v[k] = __half2float(xwp[((r[k] & 0xFFFF) << 6) + lane]);
#pragma unroll
        for (int k = 0; k < 16; ++k) acc += v[k];
    }
    if (e + 8 <= n) {
        int r[8];
#pragma unroll
        for (int k = 0; k < 8; ++k) r[k] = er[s0 + e + k];
        float v[8];
#pragma unroll
        for (int k = 0; k < 8; ++k) v[k] = __half2float(xwp[((r[k] & 0xFFFF) << 6) + lane]);
#pragma unroll
        for (int k = 0; k < 8; ++k) acc += v[k];
        e += 8;
    }
    if (e + 4 <= n) {
        int r[4];
#pragma unroll
        for (int k = 0; k < 4; ++k) r[k] = er[s0 + e + k];
        float v[4];
#pragma unroll
        for (int k = 0; k < 4; ++k) v[k] = __half2float(xwp[((r[k] & 0xFFFF) << 6) + lane]);
#pragma unroll
        for (int k = 0; k < 4; ++k) acc += v[k];
        e += 4;
    }
    for (; e < n; ++e)
        acc += __half2float(xwp[((er[s0 + e] & 0xFFFF) << 6) + lane]);
    return acc;
}

// ---------------- layer1: per-node agg + tanh + @W2, writes prescaled fp16 xw2 ----------------
__global__ __launch_bounds__(256) void aggA_kernel(
    const __half* __restrict__ xwp, const int* __restrict__ erec2,
    const int* __restrict__ nodeStart, const int* __restrict__ deg,
    const float* __restrict__ b1v, const float* __restrict__ W2,
    __half* __restrict__ xw2p) {
    __shared__ float W2l[64 * 64];             // 16 KB
    __shared__ float rowS[4][64];
    int t = threadIdx.x;
    for (int i = t; i < 1024; i += 256)
        reinterpret_cast<float4*>(W2l)[i] = reinterpret_cast<const float4*>(W2)[i];
    __syncthreads();
    int node = __builtin_amdgcn_readfirstlane(blockIdx.x * 4 + (t >> 6));
    if (node >= N_NODES) return;
    int lane = t & 63, wib = t >> 6;
    int s0 = __builtin_amdgcn_readfirstlane(nodeStart[node]);
    int n  = __builtin_amdgcn_readfirstlane(deg[node]);
    float acc = gatherN(xwp, erec2, s0, n, lane);
    float selfv = __half2float(xwp[(node << 6) + lane]);
    float di = rsqrtf((float)n + 1.0f);
    float h = tanhf((acc + selfv) * di + b1v[lane]);
    rowS[wib][lane] = h;                       // wave-private
    float o = 0.0f;
#pragma unroll
    for (int f4 = 0; f4 < 16; ++f4) {
        float4 rv = reinterpret_cast<const float4*>(&rowS[wib][0])[f4];
        o += rv.x * W2l[(f4 * 4 + 0) * 64 + lane];
        o += rv.y * W2l[(f4 * 4 + 1) * 64 + lane];
        o += rv.z * W2l[(f4 * 4 + 2) * 64 + lane];
        o += rv.w * W2l[(f4 * 4 + 3) * 64 + lane];
    }
    xw2p[(node << 6) + lane] = __float2half_rn(o * di);   // prescale for layer 2
}

// ---------------- layer2: per-node agg + emb + tanh + head + log_softmax ----------------
__global__ __launch_bounds__(256) void aggB_kernel(
    const __half* __restrict__ xw2p, const int* __restrict__ erec2,
    const int* __restrict__ nodeStart, const int* __restrict__ deg,
    const float* __restrict__ b2v, const float* __restrict__ Wc,
    const float* __restrict__ bc, float* __restrict__ embOut,
    float* __restrict__ logitsOut) {
    __shared__ float Wcl[64 * 32];             // 8 KB
    __shared__ float rowS[4][64];
    __shared__ float bcl[32];
    int t = threadIdx.x;
    for (int i = t; i < 512; i += 256)         // FIX R10: 512 float4 with 256 threads
        reinterpret_cast<float4*>(Wcl)[i] = reinterpret_cast<const float4*>(Wc)[i];
    if (t < 32) bcl[t] = bc[t];
    __syncthreads();
    int node = __builtin_amdgcn_readfirstlane(blockIdx.x * 4 + (t >> 6));
    if (node >= N_NODES) return;
    int lane = t & 63, wib = t >> 6;
    int s0 = __builtin_amdgcn_readfirstlane(nodeStart[node]);
    int n  = __builtin_amdgcn_readfirstlane(deg[node]);
    float acc = gatherN(xw2p, erec2, s0, n, lane);
    float selfv = __half2float(xw2p[(node << 6) + lane]);
    float di = rsqrtf((float)n + 1.0f);
    float v = (acc + selfv) * di + b2v[lane];
    embOut[(node << 6) + lane] = v;
    rowS[wib][lane] = tanhf(v);                // wave-private
    int j = lane & 31, half = lane >> 5;
    float p = half ? 0.0f : bcl[j];
#pragma unroll
    for (int f4 = 0; f4 < 8; ++f4) {
        float4 rv = reinterpret_cast<const float4*>(&rowS[wib][half * 32])[f4];
        int fb = half * 32 + f4 * 4;
        p += rv.x * Wcl[(fb + 0) * 32 + j];
        p += rv.y * Wcl[(fb + 1) * 32 + j];
        p += rv.z * Wcl[(fb + 2) * 32 + j];
        p += rv.w * Wcl[(fb + 3) * 32 + j];
    }
    p += __shfl_down(p, 32);                   // lanes 0..31 hold full logits
    float m = p;
#pragma unroll
    for (int o = 16; o > 0; o >>= 1) m = fmaxf(m, __shfl_xor(m, o, 32));
    float ex = __expf(p - m);
    float s = ex;
#pragma unroll
    for (int o = 16; o > 0; o >>= 1) s += __shfl_xor(s, o, 32);
    if (half == 0) logitsOut[node * 32 + j] = p - m - logf(s);
}

extern "C" void kernel_launch(void* const* d_in, const int* in_sizes, int n_in,
                              void* d_out, int out_size, void* d_ws, size_t ws_size,
                              hipStream_t stream) {
    const float* x   = (const float*)d_in[0];
    const int*   ei  = (const int*)d_in[1];
    const float* W1  = (const float*)d_in[2];
    const float* b1  = (const float*)d_in[3];
    const float* W2  = (const float*)d_in[4];
    const float* b2  = (const float*)d_in[5];
    const float* Wp1 = (const float*)d_in[6];
    const float* bp1 = (const float*)d_in[7];
    const float* Wp2 = (const float*)d_in[8];
    const float* bp2 = (const float*)d_in[9];

    char* ws = (char*)d_ws;
    int*    gcnt   = (int*)(ws + OFF_GCNT);
    int*    gbase  = (int*)(ws + OFF_GBASE);
    int*    deg    = (int*)(ws + OFF_DEG);
    int*    nstart = (int*)(ws + OFF_NSTART);
    int*    perblk = (int*)(ws + OFF_PERBLK);
    int*    erec   = (int*)(ws + OFF_EREC);
    int*    erec2  = (int*)(ws + OFF_EREC2);
    __half* xwp    = (__half*)(ws + OFF_XW);
    __half* xw2p   = (__half*)(ws + OFF_XW2);
    float*  Wc     = (float*)(ws + OFF_WC);
    float*  bc     = (float*)(ws + OFF_BC);

    float* emb_out    = (float*)d_out;                        // [N,64]
    float* logits_out = (float*)d_out + (size_t)N_NODES * 64; // [N,32]

    zero_kernel<<<1, 256, 0, stream>>>((int4*)(ws + OFF_GCNT));
    hist_kernel<<<NBLK_BIN, BIN_THREADS, 0, stream>>>(ei, gcnt, perblk);
    scanP_kernel<<<1, 1024, 0, stream>>>(gcnt, gbase, Wp1, bp1, Wp2, bp2, Wc, bc);
    scat_kernel<<<NBLK_BIN, BIN_THREADS, 0, stream>>>(ei, gbase, perblk, erec);
    sortK_kernel<<<NBUCK, 512, 0, stream>>>(erec, gbase, erec2, nstart, deg);

    gemm64_kernel<IN_DIM><<<(N_NODES + 255) / 256, 256, 0, stream>>>(x, W1, deg, xwp, N_NODES);
    aggA_kernel<<<(N_NODES + 3) / 4, 256, 0, stream>>>(xwp, erec2, nstart, deg, b1, W2, xw2p);
    aggB_kernel<<<(N_NODES + 3) / 4, 256, 0, stream>>>(xw2p, erec2, nstart, deg, b2, Wc, bc, emb_out, logits_out);
}